// Round 1
// baseline (4903.949 us; speedup 1.0000x reference)
//
#include <hip/hip_runtime.h>
#include <hip/hip_bf16.h>
#include <math.h>

// ---------------------------------------------------------------------------
// DDiTBlockCausal: B=2, S=2048, D=1024, H=16, Dh=64, MLP=4096, fp32 I/O.
// Round 0: correctness-first decomposed fp32 pipeline.
//   ln1 -> qkv gemm -> rope -> causal attention -> outproj(+res x)
//       -> ln2 -> mlp1(+bias,gelu) -> mlp2(+bias,+res x2) -> d_out
// ---------------------------------------------------------------------------

#define B_ 2
#define S_ 2048
#define D_ 1024
#define H_ 16
#define DH_ 64
#define MLP_ 4096
#define ROWS_ (B_ * S_)   // 4096

__device__ __forceinline__ float wave_reduce_sum(float v) {
  #pragma unroll
  for (int off = 32; off > 0; off >>= 1) v += __shfl_down(v, off, 64);
  return v;
}
__device__ __forceinline__ float wave_reduce_max(float v) {
  #pragma unroll
  for (int off = 32; off > 0; off >>= 1) v = fmaxf(v, __shfl_down(v, off, 64));
  return v;
}

// ---------------- LayerNorm (one block of 256 threads per row, D=1024) -----
__global__ __launch_bounds__(256) void ln_kernel(
    const float* __restrict__ x, const float* __restrict__ w,
    float* __restrict__ y) {
  const int row = blockIdx.x;
  const float4 v = reinterpret_cast<const float4*>(x + (size_t)row * D_)[threadIdx.x];
  float s  = v.x + v.y + v.z + v.w;
  float ss = v.x * v.x + v.y * v.y + v.z * v.z + v.w * v.w;
  __shared__ float red[8];
  const int wave = threadIdx.x >> 6, lane = threadIdx.x & 63;
  const float ws1 = wave_reduce_sum(s);
  const float ws2 = wave_reduce_sum(ss);
  if (lane == 0) { red[wave] = ws1; red[4 + wave] = ws2; }
  __syncthreads();
  const float tot  = red[0] + red[1] + red[2] + red[3];
  const float tot2 = red[4] + red[5] + red[6] + red[7];
  const float mu  = tot * (1.0f / D_);
  const float var = tot2 * (1.0f / D_) - mu * mu;
  const float inv = rsqrtf(var + 1e-5f);
  const float4 wv = reinterpret_cast<const float4*>(w)[threadIdx.x];
  float4 o;
  o.x = (v.x - mu) * inv * wv.x;
  o.y = (v.y - mu) * inv * wv.y;
  o.z = (v.z - mu) * inv * wv.z;
  o.w = (v.w - mu) * inv * wv.w;
  reinterpret_cast<float4*>(y + (size_t)row * D_)[threadIdx.x] = o;
}

// ---------------- GEMM: C[M,N] = A[M,K] * W[N,K]^T, fused epilogue ---------
// FUSE bits: 1 = +bias[n], 2 = gelu, 4 = +res[m*N+n]
__device__ __forceinline__ float gelu_tanh(float u) {
  const float u3 = u * u * u;
  const float t = tanhf(0.7978845608028654f * (u + 0.044715f * u3));
  return 0.5f * u * (1.0f + t);
}

template <int FUSE>
__global__ __launch_bounds__(256) void gemm_kernel(
    const float* __restrict__ A, const float* __restrict__ W,
    const float* __restrict__ bias, const float* __restrict__ res,
    float* __restrict__ C, int M, int N, int K) {
  __shared__ float As[16][64];
  __shared__ float Bs[16][64];
  const int tx = threadIdx.x;          // 0..15 (N micro)
  const int ty = threadIdx.y;          // 0..15 (M micro)
  const int tid = ty * 16 + tx;
  const int m0 = blockIdx.y * 64;
  const int n0 = blockIdx.x * 64;
  const int lr = tid >> 2;             // 0..63 tile row
  const int lk = (tid & 3) * 4;        // 0,4,8,12
  const float* Ap = A + (size_t)(m0 + lr) * K + lk;
  const float* Wp = W + (size_t)(n0 + lr) * K + lk;

  float acc[4][4] = {};
  for (int k0 = 0; k0 < K; k0 += 16) {
    const float4 a = *reinterpret_cast<const float4*>(Ap + k0);
    const float4 b = *reinterpret_cast<const float4*>(Wp + k0);
    As[lk + 0][lr] = a.x; As[lk + 1][lr] = a.y;
    As[lk + 2][lr] = a.z; As[lk + 3][lr] = a.w;
    Bs[lk + 0][lr] = b.x; Bs[lk + 1][lr] = b.y;
    Bs[lk + 2][lr] = b.z; Bs[lk + 3][lr] = b.w;
    __syncthreads();
    #pragma unroll
    for (int k = 0; k < 16; ++k) {
      const float4 av = *reinterpret_cast<const float4*>(&As[k][ty * 4]);
      const float4 bv = *reinterpret_cast<const float4*>(&Bs[k][tx * 4]);
      const float aa[4] = {av.x, av.y, av.z, av.w};
      const float bb[4] = {bv.x, bv.y, bv.z, bv.w};
      #pragma unroll
      for (int i = 0; i < 4; ++i)
        #pragma unroll
        for (int j = 0; j < 4; ++j) acc[i][j] += aa[i] * bb[j];
    }
    __syncthreads();
  }

  #pragma unroll
  for (int i = 0; i < 4; ++i) {
    const int m = m0 + ty * 4 + i;
    #pragma unroll
    for (int j = 0; j < 4; ++j) {
      const int n = n0 + tx * 4 + j;
      float c = acc[i][j];
      if (FUSE & 1) c += bias[n];
      if (FUSE & 2) c = gelu_tanh(c);
      if (FUSE & 4) c += res[(size_t)m * N + n];
      C[(size_t)m * N + n] = c;
    }
  }
}

// ---------------- RoPE + transpose to (B,H,S,Dh) ---------------------------
__global__ __launch_bounds__(256) void rope_kernel(
    const float* __restrict__ qkv, const float* __restrict__ cosb,
    const float* __restrict__ sinb, float* __restrict__ Qo,
    float* __restrict__ Ko, float* __restrict__ Vo) {
  const int bs = blockIdx.x;           // b*S + s
  const int s  = bs & (S_ - 1);
  const int b  = bs >> 11;
  const int t  = threadIdx.x;
  const float* base = qkv + (size_t)bs * (3 * D_);
  #pragma unroll
  for (int i = 0; i < 12; ++i) {
    const int e = i * 256 + t;         // 0..3071
    const int which = e >> 10;         // 0=q,1=k,2=v
    const int rem = e & 1023;
    const int h = rem >> 6;
    const int d = rem & 63;
    const float val = base[e];
    float out;
    if (which == 2) {
      out = val;
    } else if (d < 32) {
      const float c  = cosb[s * 64 + d];
      const float sn = sinb[s * 64 + d];
      out = val * c - base[e + 32] * sn;
    } else {
      const float c  = cosb[s * 64 + d - 32];
      const float sn = sinb[s * 64 + d - 32];
      out = val * c + base[e - 32] * sn;
    }
    const size_t oidx = (((size_t)(b * H_ + h)) * S_ + s) * DH_ + d;
    if (which == 0)      Qo[oidx] = out;
    else if (which == 1) Ko[oidx] = out;
    else                 Vo[oidx] = out;
  }
}

// ---------------- Causal attention: one block per (q, b*h) -----------------
// Q,K,V in (B,H,S,Dh); O written in (B,S,H,Dh) == (B,S,D)
__global__ __launch_bounds__(256) void attn_kernel(
    const float* __restrict__ Q, const float* __restrict__ K,
    const float* __restrict__ V, float* __restrict__ O) {
  const int q  = blockIdx.x;
  const int bh = blockIdx.y;           // b*H + h
  const float* Qp = Q + ((size_t)bh * S_ + q) * DH_;
  const float* Kp = K + (size_t)bh * S_ * DH_;
  const float* Vp = V + (size_t)bh * S_ * DH_;
  __shared__ float qs[64];
  __shared__ float p[S_];
  __shared__ float red[8];
  __shared__ float os[4][64];
  const int t = threadIdx.x;
  if (t < 64) qs[t] = Qp[t];
  __syncthreads();

  const int nk = q + 1;
  float mx = -3.4e38f;
  for (int j = t; j < nk; j += 256) {
    const float* kr = Kp + (size_t)j * DH_;
    float dot = 0.0f;
    #pragma unroll
    for (int d = 0; d < 64; d += 4) {
      const float4 kv = *reinterpret_cast<const float4*>(kr + d);
      dot += qs[d] * kv.x + qs[d + 1] * kv.y + qs[d + 2] * kv.z + qs[d + 3] * kv.w;
    }
    dot *= 0.125f;                      // 1/sqrt(64)
    p[j] = dot;
    mx = fmaxf(mx, dot);
  }
  const int wave = t >> 6, lane = t & 63;
  const float wm = wave_reduce_max(mx);
  if (lane == 0) red[wave] = wm;
  __syncthreads();
  mx = fmaxf(fmaxf(red[0], red[1]), fmaxf(red[2], red[3]));

  float sum = 0.0f;
  for (int j = t; j < nk; j += 256) {
    const float e = __expf(p[j] - mx);
    p[j] = e;
    sum += e;
  }
  const float wsum = wave_reduce_sum(sum);
  if (lane == 0) red[4 + wave] = wsum;
  __syncthreads();                      // also makes all p[j] visible
  sum = red[4] + red[5] + red[6] + red[7];

  const int d = t & 63;
  const int g = t >> 6;
  float acc = 0.0f;
  for (int j = g; j < nk; j += 4) acc += p[j] * Vp[(size_t)j * DH_ + d];
  os[g][d] = acc;
  __syncthreads();
  if (g == 0) {
    const float r = (os[0][d] + os[1][d] + os[2][d] + os[3][d]) / sum;
    const int b = bh >> 4, h = bh & 15;
    O[(((size_t)b * S_ + q) * H_ + h) * DH_ + d] = r;
  }
}

// ---------------------------------------------------------------------------
extern "C" void kernel_launch(void* const* d_in, const int* in_sizes, int n_in,
                              void* d_out, int out_size, void* d_ws, size_t ws_size,
                              hipStream_t stream) {
  const float* x       = (const float*)d_in[0];   // (2,2048,1024)
  const float* rot_cos = (const float*)d_in[1];   // (1,2048,1,1,64)
  const float* rot_sin = (const float*)d_in[2];
  const float* ln1_w   = (const float*)d_in[3];   // (1024)
  const float* w_qkv   = (const float*)d_in[4];   // (3072,1024)
  const float* w_out   = (const float*)d_in[5];   // (1024,1024)
  const float* ln2_w   = (const float*)d_in[6];   // (1024)
  const float* w_mlp1  = (const float*)d_in[7];   // (4096,1024)
  const float* b_mlp1  = (const float*)d_in[8];   // (4096)
  const float* w_mlp2  = (const float*)d_in[9];   // (1024,4096)
  const float* b_mlp2  = (const float*)d_in[10];  // (1024)
  float* out = (float*)d_out;

  float* ws = (float*)d_ws;
  const size_t M4 = (size_t)ROWS_ * D_;           // 4M floats
  float* h1  = ws;                                // 4M  (reused for h2)
  float* qkv = ws + 1 * M4;                       // 12M (b,s,3,h,d)
  float* o   = qkv;                               // reuse after rope/attn
  float* q_r = ws + 4 * M4;                       // 4M  (B,H,S,Dh)
  float* k_r = ws + 5 * M4;                       // 4M
  float* v_r = ws + 6 * M4;                       // 4M
  float* x2  = ws + 7 * M4;                       // 4M
  float* u   = ws + 8 * M4;                       // 16M (b,s,4096)
  float* h2  = h1;
  (void)ws_size; (void)in_sizes; (void)n_in; (void)out_size;

  dim3 b256(256);
  dim3 b16x16(16, 16);

  // 1) h1 = LN(x) * ln1_w
  ln_kernel<<<dim3(ROWS_), b256, 0, stream>>>(x, ln1_w, h1);
  // 2) qkv = h1 @ w_qkv^T    (M=4096, N=3072, K=1024)
  gemm_kernel<0><<<dim3(3 * D_ / 64, ROWS_ / 64), b16x16, 0, stream>>>(
      h1, w_qkv, nullptr, nullptr, qkv, ROWS_, 3 * D_, D_);
  // 3) rope + transpose -> q_r, k_r, v_r (B,H,S,Dh)
  rope_kernel<<<dim3(ROWS_), b256, 0, stream>>>(qkv, rot_cos, rot_sin, q_r, k_r, v_r);
  // 4) causal attention -> o (B,S,H,Dh)  [o overlays dead qkv buffer]
  attn_kernel<<<dim3(S_, B_ * H_), b256, 0, stream>>>(q_r, k_r, v_r, o);
  // 5) x2 = x + o @ w_out^T   (M=4096, N=1024, K=1024)
  gemm_kernel<4><<<dim3(D_ / 64, ROWS_ / 64), b16x16, 0, stream>>>(
      o, w_out, nullptr, x, x2, ROWS_, D_, D_);
  // 6) h2 = LN(x2) * ln2_w
  ln_kernel<<<dim3(ROWS_), b256, 0, stream>>>(x2, ln2_w, h2);
  // 7) u = gelu(h2 @ w_mlp1^T + b_mlp1)  (M=4096, N=4096, K=1024)
  gemm_kernel<3><<<dim3(MLP_ / 64, ROWS_ / 64), b16x16, 0, stream>>>(
      h2, w_mlp1, b_mlp1, nullptr, u, ROWS_, MLP_, D_);
  // 8) out = x2 + (u @ w_mlp2^T + b_mlp2)  (M=4096, N=1024, K=4096)
  gemm_kernel<5><<<dim3(D_ / 64, ROWS_ / 64), b16x16, 0, stream>>>(
      u, w_mlp2, b_mlp2, x2, out, ROWS_, D_, MLP_);
}

// Round 2
// 1770.328 us; speedup vs baseline: 2.7701x; 2.7701x over previous
//
#include <hip/hip_runtime.h>
#include <hip/hip_bf16.h>
#include <math.h>

// ---------------------------------------------------------------------------
// DDiTBlockCausal: B=2, S=2048, D=1024, H=16, Dh=64, MLP=4096, fp32 I/O.
// Round 1: flash-style bf16 MFMA attention; fp32 GEMMs unchanged.
// ---------------------------------------------------------------------------

#define B_ 2
#define S_ 2048
#define D_ 1024
#define H_ 16
#define DH_ 64
#define MLP_ 4096
#define ROWS_ (B_ * S_)   // 4096

typedef short bf16x8 __attribute__((ext_vector_type(8)));
typedef float f32x4 __attribute__((ext_vector_type(4)));
typedef unsigned short ushort_t;

__device__ __forceinline__ float wave_reduce_sum(float v) {
  #pragma unroll
  for (int off = 32; off > 0; off >>= 1) v += __shfl_down(v, off, 64);
  return v;
}

__device__ __forceinline__ ushort_t f2bf(float v) {
  __hip_bfloat16 h = __float2bfloat16(v);
  return *(ushort_t*)&h;
}

// ---------------- LayerNorm (one block of 256 threads per row, D=1024) -----
__global__ __launch_bounds__(256) void ln_kernel(
    const float* __restrict__ x, const float* __restrict__ w,
    float* __restrict__ y) {
  const int row = blockIdx.x;
  const float4 v = reinterpret_cast<const float4*>(x + (size_t)row * D_)[threadIdx.x];
  float s  = v.x + v.y + v.z + v.w;
  float ss = v.x * v.x + v.y * v.y + v.z * v.z + v.w * v.w;
  __shared__ float red[8];
  const int wave = threadIdx.x >> 6, lane = threadIdx.x & 63;
  const float ws1 = wave_reduce_sum(s);
  const float ws2 = wave_reduce_sum(ss);
  if (lane == 0) { red[wave] = ws1; red[4 + wave] = ws2; }
  __syncthreads();
  const float tot  = red[0] + red[1] + red[2] + red[3];
  const float tot2 = red[4] + red[5] + red[6] + red[7];
  const float mu  = tot * (1.0f / D_);
  const float var = tot2 * (1.0f / D_) - mu * mu;
  const float inv = rsqrtf(var + 1e-5f);
  const float4 wv = reinterpret_cast<const float4*>(w)[threadIdx.x];
  float4 o;
  o.x = (v.x - mu) * inv * wv.x;
  o.y = (v.y - mu) * inv * wv.y;
  o.z = (v.z - mu) * inv * wv.z;
  o.w = (v.w - mu) * inv * wv.w;
  reinterpret_cast<float4*>(y + (size_t)row * D_)[threadIdx.x] = o;
}

// ---------------- GEMM: C[M,N] = A[M,K] * W[N,K]^T, fused epilogue ---------
// FUSE bits: 1 = +bias[n], 2 = gelu, 4 = +res[m*N+n]
__device__ __forceinline__ float gelu_tanh(float u) {
  const float u3 = u * u * u;
  const float t = tanhf(0.7978845608028654f * (u + 0.044715f * u3));
  return 0.5f * u * (1.0f + t);
}

template <int FUSE>
__global__ __launch_bounds__(256) void gemm_kernel(
    const float* __restrict__ A, const float* __restrict__ W,
    const float* __restrict__ bias, const float* __restrict__ res,
    float* __restrict__ C, int M, int N, int K) {
  __shared__ float As[16][64];
  __shared__ float Bs[16][64];
  const int tx = threadIdx.x;          // 0..15 (N micro)
  const int ty = threadIdx.y;          // 0..15 (M micro)
  const int tid = ty * 16 + tx;
  const int m0 = blockIdx.y * 64;
  const int n0 = blockIdx.x * 64;
  const int lr = tid >> 2;             // 0..63 tile row
  const int lk = (tid & 3) * 4;        // 0,4,8,12
  const float* Ap = A + (size_t)(m0 + lr) * K + lk;
  const float* Wp = W + (size_t)(n0 + lr) * K + lk;

  float acc[4][4] = {};
  for (int k0 = 0; k0 < K; k0 += 16) {
    const float4 a = *reinterpret_cast<const float4*>(Ap + k0);
    const float4 b = *reinterpret_cast<const float4*>(Wp + k0);
    As[lk + 0][lr] = a.x; As[lk + 1][lr] = a.y;
    As[lk + 2][lr] = a.z; As[lk + 3][lr] = a.w;
    Bs[lk + 0][lr] = b.x; Bs[lk + 1][lr] = b.y;
    Bs[lk + 2][lr] = b.z; Bs[lk + 3][lr] = b.w;
    __syncthreads();
    #pragma unroll
    for (int k = 0; k < 16; ++k) {
      const float4 av = *reinterpret_cast<const float4*>(&As[k][ty * 4]);
      const float4 bv = *reinterpret_cast<const float4*>(&Bs[k][tx * 4]);
      const float aa[4] = {av.x, av.y, av.z, av.w};
      const float bb[4] = {bv.x, bv.y, bv.z, bv.w};
      #pragma unroll
      for (int i = 0; i < 4; ++i)
        #pragma unroll
        for (int j = 0; j < 4; ++j) acc[i][j] += aa[i] * bb[j];
    }
    __syncthreads();
  }

  #pragma unroll
  for (int i = 0; i < 4; ++i) {
    const int m = m0 + ty * 4 + i;
    #pragma unroll
    for (int j = 0; j < 4; ++j) {
      const int n = n0 + tx * 4 + j;
      float c = acc[i][j];
      if (FUSE & 1) c += bias[n];
      if (FUSE & 2) c = gelu_tanh(c);
      if (FUSE & 4) c += res[(size_t)m * N + n];
      C[(size_t)m * N + n] = c;
    }
  }
}

// ---------------- RoPE + transpose to (B,H,S,Dh), bf16 out -----------------
// Q is pre-scaled by 1/sqrt(Dh) = 0.125 (exact in bf16).
__global__ __launch_bounds__(256) void rope_kernel(
    const float* __restrict__ qkv, const float* __restrict__ cosb,
    const float* __restrict__ sinb, ushort_t* __restrict__ Qo,
    ushort_t* __restrict__ Ko, ushort_t* __restrict__ Vo) {
  const int bs = blockIdx.x;           // b*S + s
  const int s  = bs & (S_ - 1);
  const int b  = bs >> 11;
  const int t  = threadIdx.x;
  const float* base = qkv + (size_t)bs * (3 * D_);
  #pragma unroll
  for (int i = 0; i < 12; ++i) {
    const int e = i * 256 + t;         // 0..3071
    const int which = e >> 10;         // 0=q,1=k,2=v
    const int rem = e & 1023;
    const int h = rem >> 6;
    const int d = rem & 63;
    const float val = base[e];
    float out;
    if (which == 2) {
      out = val;
    } else if (d < 32) {
      out = val * cosb[s * 64 + d] - base[e + 32] * sinb[s * 64 + d];
    } else {
      out = val * cosb[s * 64 + d - 32] + base[e - 32] * sinb[s * 64 + d - 32];
    }
    const size_t oidx = (((size_t)(b * H_ + h)) * S_ + s) * DH_ + d;
    if (which == 0)      Qo[oidx] = f2bf(out * 0.125f);
    else if (which == 1) Ko[oidx] = f2bf(out);
    else                 Vo[oidx] = f2bf(out);
  }
}

// ---------------- Flash attention, bf16 MFMA -------------------------------
// Q,K,V bf16 in (B,H,S,Dh). O fp32 in (B,S,H,Dh) == (B,S,D).
// Block = 4 waves; each wave owns a 16-query tile of a 64-query block.
// K-chunks of 32 keys staged in LDS; online softmax in fp32.
#define KPAD 72   // K row stride (ushorts)
#define VPAD 68   // V row stride (ushorts)
#define PPAD 40   // P row stride (ushorts)

__global__ __launch_bounds__(256) void attn_kernel(
    const ushort_t* __restrict__ Qb, const ushort_t* __restrict__ Kb,
    const ushort_t* __restrict__ Vb, float* __restrict__ O) {
  const int qb = gridDim.x - 1 - blockIdx.x;   // big tiles first
  const int q0 = qb * 64;
  const int bh = blockIdx.y;
  const int b = bh >> 4, h = bh & 15;
  const int t = threadIdx.x;
  const int wave = t >> 6;
  const int lane = t & 63;
  const int l15 = lane & 15;
  const int quad = lane >> 4;

  __shared__ ushort_t Klds[32 * KPAD];
  __shared__ ushort_t Vlds[32 * VPAD];
  __shared__ ushort_t Plds[4][16 * PPAD];

  // Q A-fragments (dh 0..31 and 32..63), loaded once.
  const int qrow = q0 + wave * 16 + l15;
  const ushort_t* qptr = Qb + ((size_t)bh * S_ + qrow) * DH_ + quad * 8;
  const bf16x8 qa0 = *(const bf16x8*)(qptr);
  const bf16x8 qa1 = *(const bf16x8*)(qptr + 32);

  f32x4 o_acc[4] = {};                 // 16 q x 64 dh, C-layout per nt
  float m_run[4], l_run[4];
  #pragma unroll
  for (int r = 0; r < 4; ++r) { m_run[r] = -1e30f; l_run[r] = 0.0f; }

  const int nchunks = q0 / 32 + 2;
  for (int c = 0; c < nchunks; ++c) {
    const int k0 = c * 32;
    __syncthreads();                   // LDS reuse fence
    {
      const int key = t >> 3, dh8 = (t & 7) * 8;
      *(bf16x8*)&Klds[key * KPAD + dh8] =
          *(const bf16x8*)(Kb + ((size_t)bh * S_ + k0 + key) * DH_ + dh8);
      *(bf16x8*)&Vlds[key * VPAD + dh8] =
          *(const bf16x8*)(Vb + ((size_t)bh * S_ + k0 + key) * DH_ + dh8);
    }
    __syncthreads();

    // S = Q K^T  (16 q x 32 keys, two 16-col n-tiles)
    f32x4 s[2] = {};
    #pragma unroll
    for (int nt = 0; nt < 2; ++nt) {
      const bf16x8 kb0 = *(const bf16x8*)&Klds[(nt * 16 + l15) * KPAD + quad * 8];
      const bf16x8 kb1 = *(const bf16x8*)&Klds[(nt * 16 + l15) * KPAD + 32 + quad * 8];
      s[nt] = __builtin_amdgcn_mfma_f32_16x16x32_bf16(qa0, kb0, s[nt], 0, 0, 0);
      s[nt] = __builtin_amdgcn_mfma_f32_16x16x32_bf16(qa1, kb1, s[nt], 0, 0, 0);
    }

    // causal mask + online softmax (rows = quad*4+r, cols = l15)
    float p0s[4], p1s[4];
    #pragma unroll
    for (int r = 0; r < 4; ++r) {
      const int query = q0 + wave * 16 + quad * 4 + r;
      float s0 = s[0][r], s1 = s[1][r];
      if (k0 + l15 > query)      s0 = -1e30f;
      if (k0 + 16 + l15 > query) s1 = -1e30f;
      float mx = fmaxf(s0, s1);
      #pragma unroll
      for (int off = 1; off < 16; off <<= 1) mx = fmaxf(mx, __shfl_xor(mx, off, 64));
      const float m_new = fmaxf(m_run[r], mx);
      const float alpha = __expf(m_run[r] - m_new);
      const float p0 = __expf(s0 - m_new);
      const float p1 = __expf(s1 - m_new);
      float rs = p0 + p1;
      #pragma unroll
      for (int off = 1; off < 16; off <<= 1) rs += __shfl_xor(rs, off, 64);
      l_run[r] = l_run[r] * alpha + rs;
      m_run[r] = m_new;
      #pragma unroll
      for (int nt = 0; nt < 4; ++nt) o_acc[nt][r] *= alpha;
      p0s[r] = p0; p1s[r] = p1;
    }

    // P: C-layout -> per-wave LDS -> A-layout (bf16)
    #pragma unroll
    for (int r = 0; r < 4; ++r) {
      Plds[wave][(quad * 4 + r) * PPAD + l15]      = f2bf(p0s[r]);
      Plds[wave][(quad * 4 + r) * PPAD + 16 + l15] = f2bf(p1s[r]);
    }
    const bf16x8 pa = *(const bf16x8*)&Plds[wave][l15 * PPAD + quad * 8];

    // O += P V   (contraction over 32 keys; 4 dh n-tiles)
    #pragma unroll
    for (int nt = 0; nt < 4; ++nt) {
      bf16x8 vb;
      #pragma unroll
      for (int j = 0; j < 8; ++j)
        vb[j] = (short)Vlds[(quad * 8 + j) * VPAD + nt * 16 + l15];
      o_acc[nt] = __builtin_amdgcn_mfma_f32_16x16x32_bf16(pa, vb, o_acc[nt], 0, 0, 0);
    }
  }

  // epilogue: normalize, store fp32 to (B,S,H,Dh)
  #pragma unroll
  for (int r = 0; r < 4; ++r) {
    const int q = q0 + wave * 16 + quad * 4 + r;
    const float inv = 1.0f / l_run[r];
    #pragma unroll
    for (int nt = 0; nt < 4; ++nt)
      O[(((size_t)b * S_ + q) * H_ + h) * DH_ + nt * 16 + l15] = o_acc[nt][r] * inv;
  }
}

// ---------------------------------------------------------------------------
extern "C" void kernel_launch(void* const* d_in, const int* in_sizes, int n_in,
                              void* d_out, int out_size, void* d_ws, size_t ws_size,
                              hipStream_t stream) {
  const float* x       = (const float*)d_in[0];
  const float* rot_cos = (const float*)d_in[1];
  const float* rot_sin = (const float*)d_in[2];
  const float* ln1_w   = (const float*)d_in[3];
  const float* w_qkv   = (const float*)d_in[4];
  const float* w_out   = (const float*)d_in[5];
  const float* ln2_w   = (const float*)d_in[6];
  const float* w_mlp1  = (const float*)d_in[7];
  const float* b_mlp1  = (const float*)d_in[8];
  const float* w_mlp2  = (const float*)d_in[9];
  const float* b_mlp2  = (const float*)d_in[10];
  float* out = (float*)d_out;

  float* ws = (float*)d_ws;
  const size_t M4 = (size_t)ROWS_ * D_;                 // 4M floats
  float* h1  = ws;                                      // 4M
  float* qkv = ws + 1 * M4;                             // 12M
  float* o   = qkv;                                     // reuse after attn
  float* x2  = ws + 4 * M4;                             // 4M
  float* u   = ws + 5 * M4;                             // 16M
  ushort_t* q_bf = (ushort_t*)(ws + 9 * M4);            // 4M ushorts
  ushort_t* k_bf = (ushort_t*)(ws + 9 * M4 + M4 / 2);
  ushort_t* v_bf = (ushort_t*)(ws + 10 * M4);
  float* h2 = h1;
  (void)ws_size; (void)in_sizes; (void)n_in; (void)out_size;

  dim3 b256(256);
  dim3 b16x16(16, 16);

  ln_kernel<<<dim3(ROWS_), b256, 0, stream>>>(x, ln1_w, h1);
  gemm_kernel<0><<<dim3(3 * D_ / 64, ROWS_ / 64), b16x16, 0, stream>>>(
      h1, w_qkv, nullptr, nullptr, qkv, ROWS_, 3 * D_, D_);
  rope_kernel<<<dim3(ROWS_), b256, 0, stream>>>(qkv, rot_cos, rot_sin, q_bf, k_bf, v_bf);
  attn_kernel<<<dim3(S_ / 64, B_ * H_), b256, 0, stream>>>(q_bf, k_bf, v_bf, o);
  gemm_kernel<4><<<dim3(D_ / 64, ROWS_ / 64), b16x16, 0, stream>>>(
      o, w_out, nullptr, x, x2, ROWS_, D_, D_);
  ln_kernel<<<dim3(ROWS_), b256, 0, stream>>>(x2, ln2_w, h2);
  gemm_kernel<3><<<dim3(MLP_ / 64, ROWS_ / 64), b16x16, 0, stream>>>(
      h2, w_mlp1, b_mlp1, nullptr, u, ROWS_, MLP_, D_);
  gemm_kernel<5><<<dim3(D_ / 64, ROWS_ / 64), b16x16, 0, stream>>>(
      u, w_mlp2, b_mlp2, x2, out, ROWS_, D_, MLP_);
}

// Round 3
// 564.467 us; speedup vs baseline: 8.6877x; 3.1363x over previous
//
#include <hip/hip_runtime.h>
#include <hip/hip_bf16.h>
#include <math.h>

// ---------------------------------------------------------------------------
// DDiTBlockCausal: B=2, S=2048, D=1024, H=16, Dh=64, MLP=4096, fp32 I/O.
// Round 2: all GEMMs -> bf16 MFMA (m97 structure: 128x128 tile, BK=32,
// global_load_lds width=16). Residual stream stays fp32.
// ---------------------------------------------------------------------------

#define B_ 2
#define S_ 2048
#define D_ 1024
#define H_ 16
#define DH_ 64
#define MLP_ 4096
#define ROWS_ (B_ * S_)   // 4096

typedef short bf16x8 __attribute__((ext_vector_type(8)));
typedef float f32x4 __attribute__((ext_vector_type(4)));
typedef unsigned short ushort_t;
typedef ushort_t u16x4 __attribute__((ext_vector_type(4)));

__device__ __forceinline__ float wave_reduce_sum(float v) {
  #pragma unroll
  for (int off = 32; off > 0; off >>= 1) v += __shfl_down(v, off, 64);
  return v;
}

__device__ __forceinline__ ushort_t f2bf(float v) {
  __hip_bfloat16 h = __float2bfloat16(v);
  return *(ushort_t*)&h;
}
__device__ __forceinline__ float bf2f(ushort_t u) {
  unsigned int v = ((unsigned int)u) << 16;
  union { unsigned int i; float f; } c; c.i = v; return c.f;
}

__device__ __forceinline__ void async_copy16(const void* g, void* l) {
  __builtin_amdgcn_global_load_lds(
      (const __attribute__((address_space(1))) void*)g,
      (__attribute__((address_space(3))) void*)l, 16, 0, 0);
}

// ---------------- weight cast fp32 -> bf16 (4 tensors, blockIdx.y picks) ---
__global__ __launch_bounds__(256) void cast_w_kernel(
    const float* __restrict__ s0, ushort_t* __restrict__ d0, int n0,
    const float* __restrict__ s1, ushort_t* __restrict__ d1, int n1,
    const float* __restrict__ s2, ushort_t* __restrict__ d2, int n2,
    const float* __restrict__ s3, ushort_t* __restrict__ d3, int n3) {
  const float* s; ushort_t* d; int n;
  switch (blockIdx.y) {
    case 0: s = s0; d = d0; n = n0; break;
    case 1: s = s1; d = d1; n = n1; break;
    case 2: s = s2; d = d2; n = n2; break;
    default: s = s3; d = d3; n = n3; break;
  }
  const int i = (blockIdx.x * 256 + threadIdx.x) * 4;
  if (i < n) {
    const float4 v = *reinterpret_cast<const float4*>(s + i);
    u16x4 o;
    o[0] = f2bf(v.x); o[1] = f2bf(v.y); o[2] = f2bf(v.z); o[3] = f2bf(v.w);
    *reinterpret_cast<u16x4*>(d + i) = o;
  }
}

// ---------------- LayerNorm: fp32 in, bf16 out -----------------------------
__global__ __launch_bounds__(256) void ln_kernel(
    const float* __restrict__ x, const float* __restrict__ w,
    ushort_t* __restrict__ y) {
  const int row = blockIdx.x;
  const float4 v = reinterpret_cast<const float4*>(x + (size_t)row * D_)[threadIdx.x];
  float s  = v.x + v.y + v.z + v.w;
  float ss = v.x * v.x + v.y * v.y + v.z * v.z + v.w * v.w;
  __shared__ float red[8];
  const int wave = threadIdx.x >> 6, lane = threadIdx.x & 63;
  const float ws1 = wave_reduce_sum(s);
  const float ws2 = wave_reduce_sum(ss);
  if (lane == 0) { red[wave] = ws1; red[4 + wave] = ws2; }
  __syncthreads();
  const float tot  = red[0] + red[1] + red[2] + red[3];
  const float tot2 = red[4] + red[5] + red[6] + red[7];
  const float mu  = tot * (1.0f / D_);
  const float var = tot2 * (1.0f / D_) - mu * mu;
  const float inv = rsqrtf(var + 1e-5f);
  const float4 wv = reinterpret_cast<const float4*>(w)[threadIdx.x];
  u16x4 o;
  o[0] = f2bf((v.x - mu) * inv * wv.x);
  o[1] = f2bf((v.y - mu) * inv * wv.y);
  o[2] = f2bf((v.z - mu) * inv * wv.z);
  o[3] = f2bf((v.w - mu) * inv * wv.w);
  reinterpret_cast<u16x4*>(y + (size_t)row * D_)[threadIdx.x] = o;
}

// ---------------- bf16 MFMA GEMM: C[M,N] = A[M,K] * W[N,K]^T ---------------
// m97 structure: 128x128 tile, 4 waves x (4x4) 16x16x32 tiles, BK=32,
// global_load_lds width=16. FUSE bits: 1=+bias, 2=gelu, 4=+res (fp32).
__device__ __forceinline__ float gelu_tanh(float u) {
  const float u3 = u * u * u;
  const float t = tanhf(0.7978845608028654f * (u + 0.044715f * u3));
  return 0.5f * u * (1.0f + t);
}

template <int FUSE, int OUTBF>
__global__ __launch_bounds__(256) void gemm_bt(
    const ushort_t* __restrict__ A, const ushort_t* __restrict__ W,
    const float* __restrict__ bias, const float* __restrict__ res,
    void* __restrict__ Cv, int M, int N, int K) {
  __shared__ ushort_t As[128 * 32];
  __shared__ ushort_t Bs[128 * 32];
  const int tid = threadIdx.x;
  const int wave = tid >> 6, lane = tid & 63;
  const int l15 = lane & 15, quad = lane >> 4;
  const int m0 = blockIdx.y * 128, n0 = blockIdx.x * 128;
  const int wm = (wave & 1) * 64, wn = (wave >> 1) * 64;

  const int srow = tid >> 2;           // 0..63
  const int scol = (tid & 3) * 8;      // 0,8,16,24 (elements)
  const ushort_t* Ag = A + (size_t)(m0 + srow) * K + scol;
  const ushort_t* Wg = W + (size_t)(n0 + srow) * K + scol;

  f32x4 acc[4][4] = {};

  for (int k0 = 0; k0 < K; k0 += 32) {
    __syncthreads();                   // protect LDS from previous iteration
    async_copy16(Ag + k0,            &As[srow * 32 + scol]);
    async_copy16(Ag + 64 * K + k0,   &As[(64 + srow) * 32 + scol]);
    async_copy16(Wg + k0,            &Bs[srow * 32 + scol]);
    async_copy16(Wg + 64 * K + k0,   &Bs[(64 + srow) * 32 + scol]);
    __syncthreads();                   // drains vmcnt

    bf16x8 af[4], bfr[4];
    #pragma unroll
    for (int i = 0; i < 4; ++i) {
      af[i]  = *(const bf16x8*)&As[(wm + i * 16 + l15) * 32 + quad * 8];
      bfr[i] = *(const bf16x8*)&Bs[(wn + i * 16 + l15) * 32 + quad * 8];
    }
    #pragma unroll
    for (int i = 0; i < 4; ++i)
      #pragma unroll
      for (int j = 0; j < 4; ++j)
        acc[i][j] = __builtin_amdgcn_mfma_f32_16x16x32_bf16(af[i], bfr[j], acc[i][j], 0, 0, 0);
  }

  #pragma unroll
  for (int i = 0; i < 4; ++i) {
    #pragma unroll
    for (int r = 0; r < 4; ++r) {
      const int m = m0 + wm + i * 16 + quad * 4 + r;
      #pragma unroll
      for (int j = 0; j < 4; ++j) {
        const int n = n0 + wn + j * 16 + l15;
        float c = acc[i][j][r];
        if (FUSE & 1) c += bias[n];
        if (FUSE & 2) c = gelu_tanh(c);
        if (FUSE & 4) c += res[(size_t)m * N + n];
        if (OUTBF) ((ushort_t*)Cv)[(size_t)m * N + n] = f2bf(c);
        else       ((float*)Cv)[(size_t)m * N + n]   = c;
      }
    }
  }
}

// ---------------- RoPE + transpose to (B,H,S,Dh), bf16 in/out --------------
// Q pre-scaled by 1/sqrt(Dh) = 0.125 (exact in bf16).
__global__ __launch_bounds__(256) void rope_kernel(
    const ushort_t* __restrict__ qkv, const float* __restrict__ cosb,
    const float* __restrict__ sinb, ushort_t* __restrict__ Qo,
    ushort_t* __restrict__ Ko, ushort_t* __restrict__ Vo) {
  const int bs = blockIdx.x;           // b*S + s
  const int s  = bs & (S_ - 1);
  const int b  = bs >> 11;
  const int t  = threadIdx.x;
  const ushort_t* base = qkv + (size_t)bs * (3 * D_);
  #pragma unroll
  for (int i = 0; i < 12; ++i) {
    const int e = i * 256 + t;         // 0..3071
    const int which = e >> 10;         // 0=q,1=k,2=v
    const int rem = e & 1023;
    const int h = rem >> 6;
    const int d = rem & 63;
    const float val = bf2f(base[e]);
    float out;
    if (which == 2) {
      out = val;
    } else if (d < 32) {
      out = val * cosb[s * 64 + d] - bf2f(base[e + 32]) * sinb[s * 64 + d];
    } else {
      out = val * cosb[s * 64 + d - 32] + bf2f(base[e - 32]) * sinb[s * 64 + d - 32];
    }
    const size_t oidx = (((size_t)(b * H_ + h)) * S_ + s) * DH_ + d;
    if (which == 0)      Qo[oidx] = f2bf(out * 0.125f);
    else if (which == 1) Ko[oidx] = f2bf(out);
    else                 Vo[oidx] = f2bf(out);
  }
}

// ---------------- Flash attention, bf16 MFMA, bf16 out ---------------------
#define KPAD 72
#define VPAD 68
#define PPAD 40

__global__ __launch_bounds__(256) void attn_kernel(
    const ushort_t* __restrict__ Qb, const ushort_t* __restrict__ Kb,
    const ushort_t* __restrict__ Vb, ushort_t* __restrict__ O) {
  const int qb = gridDim.x - 1 - blockIdx.x;   // big tiles first
  const int q0 = qb * 64;
  const int bh = blockIdx.y;
  const int b = bh >> 4, h = bh & 15;
  const int t = threadIdx.x;
  const int wave = t >> 6;
  const int lane = t & 63;
  const int l15 = lane & 15;
  const int quad = lane >> 4;

  __shared__ ushort_t Klds[32 * KPAD];
  __shared__ ushort_t Vlds[32 * VPAD];
  __shared__ ushort_t Plds[4][16 * PPAD];

  const int qrow = q0 + wave * 16 + l15;
  const ushort_t* qptr = Qb + ((size_t)bh * S_ + qrow) * DH_ + quad * 8;
  const bf16x8 qa0 = *(const bf16x8*)(qptr);
  const bf16x8 qa1 = *(const bf16x8*)(qptr + 32);

  f32x4 o_acc[4] = {};
  float m_run[4], l_run[4];
  #pragma unroll
  for (int r = 0; r < 4; ++r) { m_run[r] = -1e30f; l_run[r] = 0.0f; }

  const int nchunks = q0 / 32 + 2;
  for (int c = 0; c < nchunks; ++c) {
    const int k0 = c * 32;
    __syncthreads();
    {
      const int key = t >> 3, dh8 = (t & 7) * 8;
      *(bf16x8*)&Klds[key * KPAD + dh8] =
          *(const bf16x8*)(Kb + ((size_t)bh * S_ + k0 + key) * DH_ + dh8);
      *(bf16x8*)&Vlds[key * VPAD + dh8] =
          *(const bf16x8*)(Vb + ((size_t)bh * S_ + k0 + key) * DH_ + dh8);
    }
    __syncthreads();

    f32x4 s[2] = {};
    #pragma unroll
    for (int nt = 0; nt < 2; ++nt) {
      const bf16x8 kb0 = *(const bf16x8*)&Klds[(nt * 16 + l15) * KPAD + quad * 8];
      const bf16x8 kb1 = *(const bf16x8*)&Klds[(nt * 16 + l15) * KPAD + 32 + quad * 8];
      s[nt] = __builtin_amdgcn_mfma_f32_16x16x32_bf16(qa0, kb0, s[nt], 0, 0, 0);
      s[nt] = __builtin_amdgcn_mfma_f32_16x16x32_bf16(qa1, kb1, s[nt], 0, 0, 0);
    }

    float p0s[4], p1s[4];
    #pragma unroll
    for (int r = 0; r < 4; ++r) {
      const int query = q0 + wave * 16 + quad * 4 + r;
      float s0 = s[0][r], s1 = s[1][r];
      if (k0 + l15 > query)      s0 = -1e30f;
      if (k0 + 16 + l15 > query) s1 = -1e30f;
      float mx = fmaxf(s0, s1);
      #pragma unroll
      for (int off = 1; off < 16; off <<= 1) mx = fmaxf(mx, __shfl_xor(mx, off, 64));
      const float m_new = fmaxf(m_run[r], mx);
      const float alpha = __expf(m_run[r] - m_new);
      const float p0 = __expf(s0 - m_new);
      const float p1 = __expf(s1 - m_new);
      float rs = p0 + p1;
      #pragma unroll
      for (int off = 1; off < 16; off <<= 1) rs += __shfl_xor(rs, off, 64);
      l_run[r] = l_run[r] * alpha + rs;
      m_run[r] = m_new;
      #pragma unroll
      for (int nt = 0; nt < 4; ++nt) o_acc[nt][r] *= alpha;
      p0s[r] = p0; p1s[r] = p1;
    }

    #pragma unroll
    for (int r = 0; r < 4; ++r) {
      Plds[wave][(quad * 4 + r) * PPAD + l15]      = f2bf(p0s[r]);
      Plds[wave][(quad * 4 + r) * PPAD + 16 + l15] = f2bf(p1s[r]);
    }
    const bf16x8 pa = *(const bf16x8*)&Plds[wave][l15 * PPAD + quad * 8];

    #pragma unroll
    for (int nt = 0; nt < 4; ++nt) {
      bf16x8 vb;
      #pragma unroll
      for (int j = 0; j < 8; ++j)
        vb[j] = (short)Vlds[(quad * 8 + j) * VPAD + nt * 16 + l15];
      o_acc[nt] = __builtin_amdgcn_mfma_f32_16x16x32_bf16(pa, vb, o_acc[nt], 0, 0, 0);
    }
  }

  #pragma unroll
  for (int r = 0; r < 4; ++r) {
    const int q = q0 + wave * 16 + quad * 4 + r;
    const float inv = 1.0f / l_run[r];
    #pragma unroll
    for (int nt = 0; nt < 4; ++nt)
      O[(((size_t)b * S_ + q) * H_ + h) * DH_ + nt * 16 + l15] =
          f2bf(o_acc[nt][r] * inv);
  }
}

// ---------------------------------------------------------------------------
extern "C" void kernel_launch(void* const* d_in, const int* in_sizes, int n_in,
                              void* d_out, int out_size, void* d_ws, size_t ws_size,
                              hipStream_t stream) {
  const float* x       = (const float*)d_in[0];
  const float* rot_cos = (const float*)d_in[1];
  const float* rot_sin = (const float*)d_in[2];
  const float* ln1_w   = (const float*)d_in[3];
  const float* w_qkv   = (const float*)d_in[4];
  const float* w_out   = (const float*)d_in[5];
  const float* ln2_w   = (const float*)d_in[6];
  const float* w_mlp1  = (const float*)d_in[7];
  const float* b_mlp1  = (const float*)d_in[8];
  const float* w_mlp2  = (const float*)d_in[9];
  const float* b_mlp2  = (const float*)d_in[10];
  float* out = (float*)d_out;

  char* wsb = (char*)d_ws;
  const size_t MB = 1u << 20;
  ushort_t* h1_bf  = (ushort_t*)(wsb + 0 * MB);    // 8 MB  (reused as h2)
  ushort_t* qkv_bf = (ushort_t*)(wsb + 8 * MB);    // 24 MB
  ushort_t* q_bf   = (ushort_t*)(wsb + 32 * MB);   // 8 MB
  ushort_t* k_bf   = (ushort_t*)(wsb + 40 * MB);   // 8 MB
  ushort_t* v_bf   = (ushort_t*)(wsb + 48 * MB);   // 8 MB
  ushort_t* o_bf   = (ushort_t*)(wsb + 56 * MB);   // 8 MB
  float*    x2     = (float*)   (wsb + 64 * MB);   // 16 MB
  ushort_t* u_bf   = (ushort_t*)(wsb + 80 * MB);   // 32 MB
  ushort_t* wq_bf  = (ushort_t*)(wsb + 112 * MB);  // 6 MB
  ushort_t* wo_bf  = (ushort_t*)(wsb + 118 * MB);  // 2 MB
  ushort_t* w1_bf  = (ushort_t*)(wsb + 120 * MB);  // 8 MB
  ushort_t* w2_bf  = (ushort_t*)(wsb + 128 * MB);  // 8 MB -> 136 MB total
  (void)ws_size; (void)in_sizes; (void)n_in; (void)out_size;

  dim3 b256(256);

  // 0) weights -> bf16
  cast_w_kernel<<<dim3(4096, 4), b256, 0, stream>>>(
      w_qkv, wq_bf, 3 * D_ * D_, w_out, wo_bf, D_ * D_,
      w_mlp1, w1_bf, MLP_ * D_, w_mlp2, w2_bf, MLP_ * D_);
  // 1) h1 = LN(x) * ln1_w -> bf16
  ln_kernel<<<dim3(ROWS_), b256, 0, stream>>>(x, ln1_w, h1_bf);
  // 2) qkv = h1 @ w_qkv^T -> bf16   (M=4096, N=3072, K=1024)
  gemm_bt<0, 1><<<dim3(3 * D_ / 128, ROWS_ / 128), b256, 0, stream>>>(
      h1_bf, wq_bf, nullptr, nullptr, qkv_bf, ROWS_, 3 * D_, D_);
  // 3) rope + transpose -> q,k,v (B,H,S,Dh) bf16
  rope_kernel<<<dim3(ROWS_), b256, 0, stream>>>(qkv_bf, rot_cos, rot_sin, q_bf, k_bf, v_bf);
  // 4) flash attention -> o (B,S,H,Dh) bf16
  attn_kernel<<<dim3(S_ / 64, B_ * H_), b256, 0, stream>>>(q_bf, k_bf, v_bf, o_bf);
  // 5) x2 = x + o @ w_out^T -> fp32  (M=4096, N=1024, K=1024)
  gemm_bt<4, 0><<<dim3(D_ / 128, ROWS_ / 128), b256, 0, stream>>>(
      o_bf, wo_bf, nullptr, x, x2, ROWS_, D_, D_);
  // 6) h2 = LN(x2) * ln2_w -> bf16
  ln_kernel<<<dim3(ROWS_), b256, 0, stream>>>(x2, ln2_w, h1_bf);
  // 7) u = gelu(h2 @ w_mlp1^T + b1) -> bf16  (M=4096, N=4096, K=1024)
  gemm_bt<3, 1><<<dim3(MLP_ / 128, ROWS_ / 128), b256, 0, stream>>>(
      h1_bf, w1_bf, b_mlp1, nullptr, u_bf, ROWS_, MLP_, D_);
  // 8) out = x2 + u @ w_mlp2^T + b2 -> fp32  (M=4096, N=1024, K=4096)
  gemm_bt<5, 0><<<dim3(D_ / 128, ROWS_ / 128), b256, 0, stream>>>(
      u_bf, w2_bf, b_mlp2, x2, out, ROWS_, D_, MLP_);
}